// Round 17
// baseline (803.670 us; speedup 1.0000x reference)
//
#include <hip/hip_runtime.h>
#include <math.h>

// ---- problem constants ----
constexpr int kHF = 361, kWF = 720;       // full grid
constexpr int kHP = 90,  kWP = 180;       // processor grid
constexpr int kCIN = 26, kCE = 48, kCOUT = 24;
constexpr int kK = 9, kNB = 6;
constexpr int kL = 90, kM = 90;
constexpr int kNL = 4, kHD = 96;
constexpr int kNP  = kHP * kWP;           // 16200
constexpr int kNPF = kHF * kWF;           // 259920

#ifndef M_PI
#define M_PI 3.14159265358979323846
#endif

// ---------------- prep (merged): DFT tables + decoder weight transpose + Legendre transposes ----------------
__global__ __launch_bounds__(256) void k_prep(float2* __restrict__ fcs, float2* __restrict__ icn,
                                              const float* __restrict__ dw, float* __restrict__ dwT,
                                              const float* __restrict__ Pw, const float* __restrict__ Pi,
                                              float* __restrict__ PwT, float* __restrict__ PiT) {
    int t = blockIdx.x * 256 + threadIdx.x;
    if (t < kM * kWP) {
        int m = t / kWP, w = t % kWP;
        double th = (2.0 * M_PI / (double)kWP) * (double)(m * w);
        double c = cos(th), s = sin(th);
        fcs[w * kM + m] = make_float2((float)(c / (double)kWP), (float)(-s / (double)kWP));
        float sc = (m == 0) ? 1.0f : 2.0f;
        icn[m * kWP + w] = make_float2(sc * (float)c, sc * (float)s);
    }
    if (t < kCOUT * kCE * kK) {
        int k = t % kK;
        int i = (t / kK) % kCE;
        int o = t / (kK * kCE);
        dwT[((size_t)i * kCOUT + o) * kK + k] = dw[t];
    }
    int N = kL * kM * kHP;
    if (t < 2 * N) {
        int mode = t >= N ? 1 : 0;
        int u = mode ? t - N : t;
        int l = u / (kM * kHP);
        int r = u % (kM * kHP);
        int m = r / kHP;
        int tt = r % kHP;
        if (mode == 0) PwT[(l * kHP + tt) * kM + m] = Pw[u];
        else           PiT[(tt * kL + l) * kM + m] = Pi[u];
    }
}

// ---------------- disco conv (encoder): simple form, OG=16 ----------------
template <int TCIN, int TCOUT, int OG>
__global__ __launch_bounds__(256) void k_disco(const float* __restrict__ src, int srcStride,
                                               const int* __restrict__ idx, const float* __restrict__ vals,
                                               const float* __restrict__ w, float* __restrict__ out, int np) {
    int gt = blockIdx.x * 256 + threadIdx.x;
    if (gt >= np * OG) return;
    int p = gt % np;
    int og = gt / np;
    constexpr int OC = TCOUT / OG;

    int qi[kNB];
#pragma unroll
    for (int n = 0; n < kNB; n++) qi[n] = idx[p * kNB + n];

    float vv[kK][kNB];
#pragma unroll
    for (int k = 0; k < kK; k++) {
        const float* vp = vals + ((size_t)k * np + p) * kNB;
#pragma unroll
        for (int n = 0; n < kNB; n += 2) {
            float2 v2 = *(const float2*)(vp + n);
            vv[k][n] = v2.x; vv[k][n + 1] = v2.y;
        }
    }

    float acc[OC];
#pragma unroll
    for (int o = 0; o < OC; o++) acc[o] = 0.0f;

    const float* wbase = w + (size_t)og * OC * TCIN * kK;

    for (int i = 0; i < TCIN; i++) {
        float xg[kNB];
#pragma unroll
        for (int n = 0; n < kNB; n++) xg[n] = src[i * srcStride + qi[n]];
        float z[kK];
#pragma unroll
        for (int k = 0; k < kK; k++) {
            float zz = 0.0f;
#pragma unroll
            for (int n = 0; n < kNB; n++) zz = fmaf(vv[k][n], xg[n], zz);
            z[k] = zz;
        }
#pragma unroll
        for (int o = 0; o < OC; o++) {
            const float* wp = wbase + ((size_t)o * TCIN + i) * kK;
            float s = acc[o];
#pragma unroll
            for (int k = 0; k < kK; k++) s = fmaf(wp[k], z[k], s);
            acc[o] = s;
        }
    }
#pragma unroll
    for (int o = 0; o < OC; o++) out[(size_t)(og * OC + o) * np + p] = acc[o];
}

// ---------------- gelu ----------------
__device__ __forceinline__ float gelu_tanh(float x) {
    float x3 = x * x * x;
    float t = tanhf(0.7978845608028654f * (x + 0.044715f * x3));
    return 0.5f * x * (1.0f + t);
}

// ---------------- fused proc layer: disco + MLP, ping-pong h ----------------
__global__ __launch_bounds__(256) void k_disco_mlp(const float* __restrict__ ho,
                                                   const int* __restrict__ idx, const float* __restrict__ vals,
                                                   const float* __restrict__ w,
                                                   const float* __restrict__ m1w, const float* __restrict__ m2w,
                                                   const float* __restrict__ lsw,
                                                   float* __restrict__ hn) {
    __shared__ float dxs[kCE][16];   // 3 KB
    __shared__ float g1[kHD][16];    // 6 KB
    int tid = threadIdx.x;
    int pp = tid & 15;
    int og = tid >> 4;               // 0..15
    int p0 = blockIdx.x * 16;
    int p = p0 + pp;
    bool active = p < kNP;

    // ---- disco phase: 3 channels per thread ----
    {
        constexpr int OC = 3;
        int qi[kNB];
        float vv[kK][kNB];
        if (active) {
#pragma unroll
            for (int n = 0; n < kNB; n++) qi[n] = idx[p * kNB + n];
#pragma unroll
            for (int k = 0; k < kK; k++) {
                const float* vp = vals + ((size_t)k * kNP + p) * kNB;
#pragma unroll
                for (int n = 0; n < kNB; n += 2) {
                    float2 v2 = *(const float2*)(vp + n);
                    vv[k][n] = v2.x; vv[k][n + 1] = v2.y;
                }
            }
        } else {
#pragma unroll
            for (int n = 0; n < kNB; n++) qi[n] = 0;
#pragma unroll
            for (int k = 0; k < kK; k++)
#pragma unroll
                for (int n = 0; n < kNB; n++) vv[k][n] = 0.0f;
        }

        float acc[OC];
#pragma unroll
        for (int o = 0; o < OC; o++) acc[o] = 0.0f;

        const float* wbase = w + (size_t)og * OC * kCE * kK;
        for (int i = 0; i < kCE; i++) {
            float xg[kNB];
#pragma unroll
            for (int n = 0; n < kNB; n++) xg[n] = ho[(size_t)i * kNP + qi[n]];
            float z[kK];
#pragma unroll
            for (int k = 0; k < kK; k++) {
                float zz = 0.0f;
#pragma unroll
                for (int n = 0; n < kNB; n++) zz = fmaf(vv[k][n], xg[n], zz);
                z[k] = zz;
            }
#pragma unroll
            for (int o = 0; o < OC; o++) {
                const float* wp = wbase + ((size_t)o * kCE + i) * kK;
                float s = acc[o];
#pragma unroll
                for (int k = 0; k < kK; k++) s = fmaf(wp[k], z[k], s);
                acc[o] = s;
            }
        }
#pragma unroll
        for (int o = 0; o < OC; o++) dxs[og * 3 + o][pp] = acc[o];
    }
    __syncthreads();

    // ---- MLP phase 1: hidden ----
    for (int j = tid; j < kHD * 16; j += 256) {
        int hh = j >> 4, pq = j & 15;
        const float* w1 = m1w + (size_t)hh * kCE;
        float a = 0.0f;
#pragma unroll 8
        for (int i = 0; i < kCE; i++) a = fmaf(w1[i], dxs[i][pq], a);
        g1[hh][pq] = gelu_tanh(a);
    }
    __syncthreads();

    // ---- MLP phase 2: output + residual into hn ----
    for (int j = tid; j < kCE * 16; j += 256) {
        int o = j >> 4, pq = j & 15;
        int p2 = p0 + pq;
        if (p2 < kNP) {
            const float* w2 = m2w + (size_t)o * kHD;
            float a = 0.0f;
#pragma unroll 8
            for (int jj = 0; jj < kHD; jj++) a = fmaf(w2[jj], g1[jj][pq], a);
            size_t q = (size_t)o * kNP + p2;
            hn[q] = ho[q] + lsw[o] * a;
        }
    }
}

// ---------------- spectral stage 1: rfft rows, 4-row register blocking ----------------
__global__ __launch_bounds__(256) void k_rfft4(const float* __restrict__ g, const float2* __restrict__ fcs,
                                               float2* __restrict__ xc) {
    __shared__ float gs[16 * kWP];   // up to 16 rows = 11.5 KB
    constexpr int NQUAD = (kCE * kHP) / 4;  // 1080
    int t0 = blockIdx.x * 256;
    int t = t0 + threadIdx.x;
    int rq0 = t0 / kM;
    int rq1 = (t0 + 255) / kM;
    if (rq1 > NQUAD - 1) rq1 = NQUAD - 1;
    int r0 = 4 * rq0;
    int nrows = 4 * (rq1 - rq0 + 1);  // <= 16
    for (int j = threadIdx.x; j < nrows * kWP; j += 256) {
        int rr = j / kWP, w = j % kWP;
        int row = r0 + rr;
        if (row < kCE * kHP) gs[j] = g[(size_t)row * kWP + w];
    }
    __syncthreads();
    if (t >= NQUAD * kM) return;
    int m = t % kM;
    int rq = t / kM;
    const float* g0 = &gs[(4 * rq - r0) * kWP];
    const float* g1 = g0 + kWP;
    const float* g2 = g1 + kWP;
    const float* g3 = g2 + kWP;
    float ar0 = 0, ai0 = 0, ar1 = 0, ai1 = 0, ar2 = 0, ai2 = 0, ar3 = 0, ai3 = 0;
#pragma unroll 4
    for (int w = 0; w < kWP; w++) {
        float2 f = fcs[w * kM + m];
        float a = g0[w], b = g1[w], c = g2[w], d = g3[w];
        ar0 = fmaf(a, f.x, ar0); ai0 = fmaf(a, f.y, ai0);
        ar1 = fmaf(b, f.x, ar1); ai1 = fmaf(b, f.y, ai1);
        ar2 = fmaf(c, f.x, ar2); ai2 = fmaf(c, f.y, ai2);
        ar3 = fmaf(d, f.x, ar3); ai3 = fmaf(d, f.y, ai3);
    }
    xc[(size_t)(4 * rq + 0) * kM + m] = make_float2(ar0, ai0);
    xc[(size_t)(4 * rq + 1) * kM + m] = make_float2(ar1, ai1);
    xc[(size_t)(4 * rq + 2) * kM + m] = make_float2(ar2, ai2);
    xc[(size_t)(4 * rq + 3) * kM + m] = make_float2(ar3, ai3);
}

// ---------------- spectral stage 2+3 fused: SHT (4-channel blocked) + channel mix ----------------
constexpr int kMT = 18;  // 90 = 5 * 18
__global__ __launch_bounds__(256) void k_sht_gmix2(const float* __restrict__ PwT,
                                                   const float2* __restrict__ xc,
                                                   const float* __restrict__ gwl,
                                                   float2* __restrict__ c2c) {
    __shared__ float2 cs[kCE][kMT];   // 6.9 KB
    int l = blockIdx.x / 5;
    int m0 = (blockIdx.x % 5) * kMT;
    int tid = threadIdx.x;

    if (tid < 12 * kMT) {
        int ig = tid / kMT, mm = tid % kMT;
        int i = ig * 4;
        int m = m0 + mm;
        float ar0 = 0, ai0 = 0, ar1 = 0, ai1 = 0, ar2 = 0, ai2 = 0, ar3 = 0, ai3 = 0;
        const float*  pw = PwT + (size_t)l * kHP * kM + m;
        const float2* x0 = xc + (size_t)(i + 0) * kHP * kM + m;
        const float2* x1 = xc + (size_t)(i + 1) * kHP * kM + m;
        const float2* x2 = xc + (size_t)(i + 2) * kHP * kM + m;
        const float2* x3 = xc + (size_t)(i + 3) * kHP * kM + m;
#pragma unroll 3
        for (int tt = 0; tt < kHP; tt++) {
            float pv = pw[tt * kM];
            float2 a = x0[tt * kM], b = x1[tt * kM], c = x2[tt * kM], d = x3[tt * kM];
            ar0 = fmaf(pv, a.x, ar0); ai0 = fmaf(pv, a.y, ai0);
            ar1 = fmaf(pv, b.x, ar1); ai1 = fmaf(pv, b.y, ai1);
            ar2 = fmaf(pv, c.x, ar2); ai2 = fmaf(pv, c.y, ai2);
            ar3 = fmaf(pv, d.x, ar3); ai3 = fmaf(pv, d.y, ai3);
        }
        cs[i + 0][mm] = make_float2(ar0, ai0);
        cs[i + 1][mm] = make_float2(ar1, ai1);
        cs[i + 2][mm] = make_float2(ar2, ai2);
        cs[i + 3][mm] = make_float2(ar3, ai3);
    }
    __syncthreads();
    for (int j = tid; j < kCE * kMT; j += 256) {
        int o = j / kMT, mm = j % kMT;
        float ar = 0.0f, ai = 0.0f;
        const float* gv = gwl + (size_t)o * kCE * kL + l;
#pragma unroll 8
        for (int i = 0; i < kCE; i++) {
            float g = gv[(size_t)i * kL];
            float2 cv = cs[i][mm];
            ar = fmaf(g, cv.x, ar);
            ai = fmaf(g, cv.y, ai);
        }
        c2c[((size_t)o * kL + l) * kM + m0 + mm] = make_float2(ar, ai);
    }
}

// ---------------- spectral stage 4+5 fused: iSHT + irfft, 4-channel blocked ----------------
constexpr int kCG = 4;
__global__ __launch_bounds__(192) void k_isht_irfft2(const float* __restrict__ PiT,
                                                     const float2* __restrict__ c2c,
                                                     const float2* __restrict__ icn,
                                                     float* __restrict__ dx) {
    __shared__ float2 xm[kCG][kM];  // 2.88 KB
    int bi = blockIdx.x;
    int t = bi % kHP;
    int c0 = (bi / kHP) * kCG;
    int tid = threadIdx.x;

    if (tid < 2 * kM) {
        int m = tid % kM;
        int cp = tid / kM;        // 0 or 1
        int ca = c0 + cp * 2;
        float ar0 = 0, ai0 = 0, ar1 = 0, ai1 = 0;
        const float*  pv  = PiT + (size_t)t * kL * kM + m;
        const float2* cva = c2c + (size_t)ca * kL * kM + m;
        const float2* cvb = cva + (size_t)kL * kM;
#pragma unroll 6
        for (int l = 0; l < kL; l++) {
            float pp = pv[(size_t)l * kM];
            float2 a = cva[(size_t)l * kM];
            float2 b = cvb[(size_t)l * kM];
            ar0 = fmaf(pp, a.x, ar0); ai0 = fmaf(pp, a.y, ai0);
            ar1 = fmaf(pp, b.x, ar1); ai1 = fmaf(pp, b.y, ai1);
        }
        xm[cp * 2 + 0][m] = make_float2(ar0, ai0);
        xm[cp * 2 + 1][m] = make_float2(ar1, ai1);
    }
    __syncthreads();
    if (tid < kWP) {
        int w = tid;
        float a0 = 0, a1 = 0, a2 = 0, a3 = 0;
#pragma unroll 6
        for (int m = 0; m < kM; m++) {
            float2 f = icn[m * kWP + w];
            float2 x0 = xm[0][m], x1 = xm[1][m], x2 = xm[2][m], x3 = xm[3][m];
            a0 = fmaf(x0.x, f.x, a0); a0 = fmaf(-x0.y, f.y, a0);
            a1 = fmaf(x1.x, f.x, a1); a1 = fmaf(-x1.y, f.y, a1);
            a2 = fmaf(x2.x, f.x, a2); a2 = fmaf(-x2.y, f.y, a2);
            a3 = fmaf(x3.x, f.x, a3); a3 = fmaf(-x3.y, f.y, a3);
        }
        dx[((size_t)(c0 + 0) * kHP + t) * kWP + w] = a0;
        dx[((size_t)(c0 + 1) * kHP + t) * kWP + w] = a1;
        dx[((size_t)(c0 + 2) * kHP + t) * kWP + w] = a2;
        dx[((size_t)(c0 + 3) * kHP + t) * kWP + w] = a3;
    }
}

// ---------------- MLP for spectral layers (in-place h update), kTP=16 ----------------
constexpr int kTP = 16;
__global__ __launch_bounds__(256) void k_mlp_f(const float* __restrict__ m1w, const float* __restrict__ m2w,
                                               const float* __restrict__ lsw, const float* __restrict__ dx,
                                               float* __restrict__ h) {
    __shared__ float xs[kCE][kTP];   // 3 KB
    __shared__ float g1[kHD][kTP];   // 6 KB
    int p0 = blockIdx.x * kTP;
    int tid = threadIdx.x;

    for (int j = tid; j < kCE * kTP; j += 256) {
        int i = j / kTP, pp = j % kTP;
        int p = p0 + pp;
        xs[i][pp] = (p < kNP) ? dx[(size_t)i * kNP + p] : 0.0f;
    }
    __syncthreads();
    for (int j = tid; j < kHD * kTP; j += 256) {
        int hh = j / kTP, pp = j % kTP;
        const float* w1 = m1w + (size_t)hh * kCE;
        float a = 0.0f;
#pragma unroll 8
        for (int i = 0; i < kCE; i++) a = fmaf(w1[i], xs[i][pp], a);
        g1[hh][pp] = gelu_tanh(a);
    }
    __syncthreads();
    for (int j = tid; j < kCE * kTP; j += 256) {
        int o = j / kTP, pp = j % kTP;
        int p = p0 + pp;
        if (p < kNP) {
            const float* w2 = m2w + (size_t)o * kHD;
            float a = 0.0f;
#pragma unroll 8
            for (int jj = 0; jj < kHD; jj++) a = fmaf(w2[jj], g1[jj][pp], a);
            size_t q = (size_t)o * kNP + p;
            h[q] = h[q] + lsw[o] * a;
        }
    }
}

// ---------------- decoder: per-point 3x3 stencil, direct from global (r8 form, unroll 4) ----------------
// Only change vs the proven 200 µs kernel: channel loop unroll 2 -> 4 (more
// independent L2 loads in flight; no structural change, compiler pipelines).
__global__ __launch_bounds__(256) void k_dconv_d(const float* __restrict__ h,
                                                 const float* __restrict__ dvals,
                                                 const float* __restrict__ dwT,
                                                 const int* __restrict__ li0, const int* __restrict__ li1,
                                                 const float* __restrict__ lwt, const int* __restrict__ oi0,
                                                 const int* __restrict__ oi1, const float* __restrict__ owt,
                                                 float* __restrict__ out) {
    int p = blockIdx.x * 256 + threadIdx.x;
    if (p >= kNPF) return;
    int lat = p / kWF;
    int p_lon = p - lat * kWF;

    int i0r[3], i1r[3];
    float awr[3];
#pragma unroll
    for (int r = 0; r < 3; r++) {
        int Lr = lat - 1 + r;
        Lr = Lr < 0 ? 0 : (Lr > kHF - 1 ? kHF - 1 : Lr);
        i0r[r] = li0[Lr]; i1r[r] = li1[Lr]; awr[r] = lwt[Lr];
    }
    int F = min(i0r[0], min(i0r[1], i0r[2]));

    float wrow[3][3];
#pragma unroll
    for (int r = 0; r < 3; r++) {
        int r0 = i0r[r] - F, r1 = i1r[r] - F;
#pragma unroll
        for (int pr = 0; pr < 3; pr++) {
            float wv = 0.0f;
            if (pr == r0) wv += 1.0f - awr[r];
            if (pr == r1) wv += awr[r];
            wrow[r][pr] = wv;
        }
    }

    int o0d[3], o1d[3];
    float owd[3];
#pragma unroll
    for (int d = 0; d < 3; d++) {
        int lm = (p_lon + d - 1 + kWF) % kWF;
        o0d[d] = oi0[lm]; o1d[d] = oi1[lm]; owd[d] = owt[lm];
    }
    int G = o0d[0];
    float wcol[3][3];
#pragma unroll
    for (int d = 0; d < 3; d++) {
        int c0 = (o0d[d] - G + kWP) % kWP;
        int c1 = (o1d[d] - G + kWP) % kWP;
#pragma unroll
        for (int pc = 0; pc < 3; pc++) {
            float wv = 0.0f;
            if (pc == c0) wv += 1.0f - owd[d];
            if (pc == c1) wv += owd[d];
            wcol[d][pc] = wv;
        }
    }

    float vv[kK][kNB];
#pragma unroll
    for (int k = 0; k < kK; k++) {
        const float* vp = dvals + ((size_t)k * kNPF + p) * kNB;
#pragma unroll
        for (int n = 0; n < kNB; n += 2) {
            float2 v2 = *(const float2*)(vp + n);
            vv[k][n] = v2.x; vv[k][n + 1] = v2.y;
        }
    }

    const int RR[kNB] = {1, 1, 1, 2, 0, 2};
    const int CC[kNB] = {1, 2, 0, 1, 1, 2};
    float ck[kK][3][3];
#pragma unroll
    for (int k = 0; k < kK; k++)
#pragma unroll
        for (int pr = 0; pr < 3; pr++)
#pragma unroll
            for (int pc = 0; pc < 3; pc++) {
                float s = 0.0f;
#pragma unroll
                for (int n = 0; n < kNB; n++)
                    s = fmaf(vv[k][n], wrow[RR[n]][pr] * wcol[CC[n]][pc], s);
                ck[k][pr][pc] = s;
            }

    int ofs[3][3];
#pragma unroll
    for (int pr = 0; pr < 3; pr++) {
        int row = F + pr; row = row > kHP - 1 ? kHP - 1 : row;
#pragma unroll
        for (int pc = 0; pc < 3; pc++) {
            int col = (G + pc) % kWP;
            ofs[pr][pc] = row * kWP + col;
        }
    }

    float acc[kCOUT];
#pragma unroll
    for (int o = 0; o < kCOUT; o++) acc[o] = 0.0f;

    const float* wp = dwT;
    const float* hi = h;
#pragma unroll 4
    for (int i = 0; i < kCE; i++) {
        float hv[3][3];
#pragma unroll
        for (int pr = 0; pr < 3; pr++)
#pragma unroll
            for (int pc = 0; pc < 3; pc++)
                hv[pr][pc] = hi[ofs[pr][pc]];
        float z[kK];
#pragma unroll
        for (int k = 0; k < kK; k++) {
            float s = 0.0f;
#pragma unroll
            for (int pr = 0; pr < 3; pr++)
#pragma unroll
                for (int pc = 0; pc < 3; pc++)
                    s = fmaf(ck[k][pr][pc], hv[pr][pc], s);
            z[k] = s;
        }
#pragma unroll
        for (int o = 0; o < kCOUT; o++) {
            float s = acc[o];
#pragma unroll
            for (int k = 0; k < kK; k++) s = fmaf(wp[o * kK + k], z[k], s);
            acc[o] = s;
        }
        wp += kCOUT * kK;
        hi += kNP;
    }

#pragma unroll
    for (int o = 0; o < kCOUT; o++) out[(size_t)o * kNPF + p] = acc[o];
}

// ---------------- host launcher ----------------
extern "C" void kernel_launch(void* const* d_in, const int* in_sizes, int n_in,
                              void* d_out, int out_size, void* d_ws, size_t ws_size,
                              hipStream_t stream) {
    const float* x         = (const float*)d_in[0];
    const int*   enc_idx   = (const int*)d_in[1];
    const float* enc_vals  = (const float*)d_in[2];
    const float* enc_w     = (const float*)d_in[3];
    const int*   proc_idx  = (const int*)d_in[4];
    const float* proc_vals = (const float*)d_in[5];
    const float* lw        = (const float*)d_in[6];
    const float* gw        = (const float*)d_in[7];
    const float* Pw        = (const float*)d_in[8];
    const float* Pi        = (const float*)d_in[9];
    const float* m1        = (const float*)d_in[10];
    const float* m2        = (const float*)d_in[11];
    const float* ls        = (const float*)d_in[12];
    const int*   li0       = (const int*)d_in[13];
    const int*   li1       = (const int*)d_in[14];
    const float* lwt       = (const float*)d_in[15];
    const int*   oi0       = (const int*)d_in[16];
    const int*   oi1       = (const int*)d_in[17];
    const float* owt       = (const float*)d_in[18];
    const int*   dec_idx   = (const int*)d_in[19];
    const float* dec_vals  = (const float*)d_in[20];
    const float* dec_w     = (const float*)d_in[21];
    float* out = (float*)d_out;
    (void)dec_idx;

    float* ws = (float*)d_ws;
    size_t off = 0;
    auto alloc = [&](size_t n) { float* p = ws + off; off += n; return p; };
    float*  h0   = alloc((size_t)kCE * kNP);
    float*  h1   = alloc((size_t)kCE * kNP);
    float2* xc   = (float2*)alloc((size_t)2 * kCE * kHP * kM);
    float2* c2c  = (float2*)alloc((size_t)2 * kCE * kL * kM);
    float*  dx   = alloc((size_t)kCE * kNP);
    float2* fcs  = (float2*)alloc((size_t)2 * kM * kWP);
    float2* icn  = (float2*)alloc((size_t)2 * kM * kWP);
    float*  PwT  = alloc((size_t)kL * kM * kHP);
    float*  PiT  = alloc((size_t)kL * kM * kHP);
    float*  dwT  = alloc((size_t)kCOUT * kCE * kK);
    (void)ws_size; (void)in_sizes; (void)n_in; (void)out_size;

    float* hbuf[2] = {h0, h1};
    int cur = 0;

    dim3 B(256);
    auto nb = [](long long n) { return dim3((unsigned)((n + 255) / 256)); };

    k_prep<<<nb(2LL * kL * kM * kHP), B, 0, stream>>>(fcs, icn, dec_w, dwT, Pw, Pi, PwT, PiT);

    // encoder (OG=16)
    k_disco<kCIN, kCE, 16><<<nb((long long)kNP * 16), B, 0, stream>>>(
        x, kNPF, enc_idx, enc_vals, enc_w, hbuf[cur], kNP);

    int nMlpBlocks = (kNP + kTP - 1) / kTP;
    for (int i = 0; i < kNL; i++) {
        if (i % 2 == 0) {
            const float* gwl = gw + (size_t)(i / 2) * kCE * kCE * kL;
            k_rfft4<<<nb((long long)(kCE * kHP / 4) * kM), B, 0, stream>>>(hbuf[cur], fcs, xc);
            k_sht_gmix2<<<dim3(kL * 5), B, 0, stream>>>(PwT, xc, gwl, c2c);
            k_isht_irfft2<<<dim3(kHP * (kCE / kCG)), dim3(192), 0, stream>>>(PiT, c2c, icn, dx);
            k_mlp_f<<<dim3(nMlpBlocks), B, 0, stream>>>(
                m1 + (size_t)i * kHD * kCE, m2 + (size_t)i * kCE * kHD, ls + (size_t)i * kCE,
                dx, hbuf[cur]);
        } else {
            const float* lwl = lw + (size_t)(i / 2) * kCE * kCE * kK;
            k_disco_mlp<<<dim3((kNP + 15) / 16), B, 0, stream>>>(
                hbuf[cur], proc_idx, proc_vals, lwl,
                m1 + (size_t)i * kHD * kCE, m2 + (size_t)i * kCE * kHD, ls + (size_t)i * kCE,
                hbuf[1 - cur]);
            cur = 1 - cur;
        }
    }

    // decoder: r8 barrier-free direct-global stencil, unroll 4
    k_dconv_d<<<nb((long long)kNPF), B, 0, stream>>>(hbuf[cur], dec_vals, dwT,
                                                     li0, li1, lwt, oi0, oi1, owt, out);
}

// Round 18
// 633.003 us; speedup vs baseline: 1.2696x; 1.2696x over previous
//
#include <hip/hip_runtime.h>
#include <math.h>

// ---- problem constants ----
constexpr int kHF = 361, kWF = 720;       // full grid
constexpr int kHP = 90,  kWP = 180;       // processor grid
constexpr int kCIN = 26, kCE = 48, kCOUT = 24;
constexpr int kK = 9, kNB = 6;
constexpr int kL = 90, kM = 90;
constexpr int kNL = 4, kHD = 96;
constexpr int kNP  = kHP * kWP;           // 16200
constexpr int kNPF = kHF * kWF;           // 259920

#ifndef M_PI
#define M_PI 3.14159265358979323846
#endif

// ---------------- prep (merged): DFT tables + decoder weight transpose + Legendre transposes ----------------
__global__ __launch_bounds__(256) void k_prep(float2* __restrict__ fcs, float2* __restrict__ icn,
                                              const float* __restrict__ dw, float* __restrict__ dwT,
                                              const float* __restrict__ Pw, const float* __restrict__ Pi,
                                              float* __restrict__ PwT, float* __restrict__ PiT) {
    int t = blockIdx.x * 256 + threadIdx.x;
    if (t < kM * kWP) {
        int m = t / kWP, w = t % kWP;
        double th = (2.0 * M_PI / (double)kWP) * (double)(m * w);
        double c = cos(th), s = sin(th);
        fcs[w * kM + m] = make_float2((float)(c / (double)kWP), (float)(-s / (double)kWP));
        float sc = (m == 0) ? 1.0f : 2.0f;
        icn[m * kWP + w] = make_float2(sc * (float)c, sc * (float)s);
    }
    if (t < kCOUT * kCE * kK) {
        int k = t % kK;
        int i = (t / kK) % kCE;
        int o = t / (kK * kCE);
        dwT[((size_t)i * kCOUT + o) * kK + k] = dw[t];
    }
    int N = kL * kM * kHP;
    if (t < 2 * N) {
        int mode = t >= N ? 1 : 0;
        int u = mode ? t - N : t;
        int l = u / (kM * kHP);
        int r = u % (kM * kHP);
        int m = r / kHP;
        int tt = r % kHP;
        if (mode == 0) PwT[(l * kHP + tt) * kM + m] = Pw[u];
        else           PiT[(tt * kL + l) * kM + m] = Pi[u];
    }
}

// ---------------- disco conv (encoder): simple form, OG=16 ----------------
template <int TCIN, int TCOUT, int OG>
__global__ __launch_bounds__(256) void k_disco(const float* __restrict__ src, int srcStride,
                                               const int* __restrict__ idx, const float* __restrict__ vals,
                                               const float* __restrict__ w, float* __restrict__ out, int np) {
    int gt = blockIdx.x * 256 + threadIdx.x;
    if (gt >= np * OG) return;
    int p = gt % np;
    int og = gt / np;
    constexpr int OC = TCOUT / OG;

    int qi[kNB];
#pragma unroll
    for (int n = 0; n < kNB; n++) qi[n] = idx[p * kNB + n];

    float vv[kK][kNB];
#pragma unroll
    for (int k = 0; k < kK; k++) {
        const float* vp = vals + ((size_t)k * np + p) * kNB;
#pragma unroll
        for (int n = 0; n < kNB; n += 2) {
            float2 v2 = *(const float2*)(vp + n);
            vv[k][n] = v2.x; vv[k][n + 1] = v2.y;
        }
    }

    float acc[OC];
#pragma unroll
    for (int o = 0; o < OC; o++) acc[o] = 0.0f;

    const float* wbase = w + (size_t)og * OC * TCIN * kK;

    for (int i = 0; i < TCIN; i++) {
        float xg[kNB];
#pragma unroll
        for (int n = 0; n < kNB; n++) xg[n] = src[i * srcStride + qi[n]];
        float z[kK];
#pragma unroll
        for (int k = 0; k < kK; k++) {
            float zz = 0.0f;
#pragma unroll
            for (int n = 0; n < kNB; n++) zz = fmaf(vv[k][n], xg[n], zz);
            z[k] = zz;
        }
#pragma unroll
        for (int o = 0; o < OC; o++) {
            const float* wp = wbase + ((size_t)o * TCIN + i) * kK;
            float s = acc[o];
#pragma unroll
            for (int k = 0; k < kK; k++) s = fmaf(wp[k], z[k], s);
            acc[o] = s;
        }
    }
#pragma unroll
    for (int o = 0; o < OC; o++) out[(size_t)(og * OC + o) * np + p] = acc[o];
}

// ---------------- gelu ----------------
__device__ __forceinline__ float gelu_tanh(float x) {
    float x3 = x * x * x;
    float t = tanhf(0.7978845608028654f * (x + 0.044715f * x3));
    return 0.5f * x * (1.0f + t);
}

// ---------------- fused proc layer: disco + MLP, ping-pong h ----------------
__global__ __launch_bounds__(256) void k_disco_mlp(const float* __restrict__ ho,
                                                   const int* __restrict__ idx, const float* __restrict__ vals,
                                                   const float* __restrict__ w,
                                                   const float* __restrict__ m1w, const float* __restrict__ m2w,
                                                   const float* __restrict__ lsw,
                                                   float* __restrict__ hn) {
    __shared__ float dxs[kCE][16];   // 3 KB
    __shared__ float g1[kHD][16];    // 6 KB
    int tid = threadIdx.x;
    int pp = tid & 15;
    int og = tid >> 4;               // 0..15
    int p0 = blockIdx.x * 16;
    int p = p0 + pp;
    bool active = p < kNP;

    // ---- disco phase: 3 channels per thread ----
    {
        constexpr int OC = 3;
        int qi[kNB];
        float vv[kK][kNB];
        if (active) {
#pragma unroll
            for (int n = 0; n < kNB; n++) qi[n] = idx[p * kNB + n];
#pragma unroll
            for (int k = 0; k < kK; k++) {
                const float* vp = vals + ((size_t)k * kNP + p) * kNB;
#pragma unroll
                for (int n = 0; n < kNB; n += 2) {
                    float2 v2 = *(const float2*)(vp + n);
                    vv[k][n] = v2.x; vv[k][n + 1] = v2.y;
                }
            }
        } else {
#pragma unroll
            for (int n = 0; n < kNB; n++) qi[n] = 0;
#pragma unroll
            for (int k = 0; k < kK; k++)
#pragma unroll
                for (int n = 0; n < kNB; n++) vv[k][n] = 0.0f;
        }

        float acc[OC];
#pragma unroll
        for (int o = 0; o < OC; o++) acc[o] = 0.0f;

        const float* wbase = w + (size_t)og * OC * kCE * kK;
        for (int i = 0; i < kCE; i++) {
            float xg[kNB];
#pragma unroll
            for (int n = 0; n < kNB; n++) xg[n] = ho[(size_t)i * kNP + qi[n]];
            float z[kK];
#pragma unroll
            for (int k = 0; k < kK; k++) {
                float zz = 0.0f;
#pragma unroll
                for (int n = 0; n < kNB; n++) zz = fmaf(vv[k][n], xg[n], zz);
                z[k] = zz;
            }
#pragma unroll
            for (int o = 0; o < OC; o++) {
                const float* wp = wbase + ((size_t)o * kCE + i) * kK;
                float s = acc[o];
#pragma unroll
                for (int k = 0; k < kK; k++) s = fmaf(wp[k], z[k], s);
                acc[o] = s;
            }
        }
#pragma unroll
        for (int o = 0; o < OC; o++) dxs[og * 3 + o][pp] = acc[o];
    }
    __syncthreads();

    // ---- MLP phase 1: hidden ----
    for (int j = tid; j < kHD * 16; j += 256) {
        int hh = j >> 4, pq = j & 15;
        const float* w1 = m1w + (size_t)hh * kCE;
        float a = 0.0f;
#pragma unroll 8
        for (int i = 0; i < kCE; i++) a = fmaf(w1[i], dxs[i][pq], a);
        g1[hh][pq] = gelu_tanh(a);
    }
    __syncthreads();

    // ---- MLP phase 2: output + residual into hn ----
    for (int j = tid; j < kCE * 16; j += 256) {
        int o = j >> 4, pq = j & 15;
        int p2 = p0 + pq;
        if (p2 < kNP) {
            const float* w2 = m2w + (size_t)o * kHD;
            float a = 0.0f;
#pragma unroll 8
            for (int jj = 0; jj < kHD; jj++) a = fmaf(w2[jj], g1[jj][pq], a);
            size_t q = (size_t)o * kNP + p2;
            hn[q] = ho[q] + lsw[o] * a;
        }
    }
}

// ---------------- spectral stage 1: rfft rows, 4-row register blocking ----------------
__global__ __launch_bounds__(256) void k_rfft4(const float* __restrict__ g, const float2* __restrict__ fcs,
                                               float2* __restrict__ xc) {
    __shared__ float gs[16 * kWP];   // up to 16 rows = 11.5 KB
    constexpr int NQUAD = (kCE * kHP) / 4;  // 1080
    int t0 = blockIdx.x * 256;
    int t = t0 + threadIdx.x;
    int rq0 = t0 / kM;
    int rq1 = (t0 + 255) / kM;
    if (rq1 > NQUAD - 1) rq1 = NQUAD - 1;
    int r0 = 4 * rq0;
    int nrows = 4 * (rq1 - rq0 + 1);  // <= 16
    for (int j = threadIdx.x; j < nrows * kWP; j += 256) {
        int rr = j / kWP, w = j % kWP;
        int row = r0 + rr;
        if (row < kCE * kHP) gs[j] = g[(size_t)row * kWP + w];
    }
    __syncthreads();
    if (t >= NQUAD * kM) return;
    int m = t % kM;
    int rq = t / kM;
    const float* g0 = &gs[(4 * rq - r0) * kWP];
    const float* g1 = g0 + kWP;
    const float* g2 = g1 + kWP;
    const float* g3 = g2 + kWP;
    float ar0 = 0, ai0 = 0, ar1 = 0, ai1 = 0, ar2 = 0, ai2 = 0, ar3 = 0, ai3 = 0;
#pragma unroll 4
    for (int w = 0; w < kWP; w++) {
        float2 f = fcs[w * kM + m];
        float a = g0[w], b = g1[w], c = g2[w], d = g3[w];
        ar0 = fmaf(a, f.x, ar0); ai0 = fmaf(a, f.y, ai0);
        ar1 = fmaf(b, f.x, ar1); ai1 = fmaf(b, f.y, ai1);
        ar2 = fmaf(c, f.x, ar2); ai2 = fmaf(c, f.y, ai2);
        ar3 = fmaf(d, f.x, ar3); ai3 = fmaf(d, f.y, ai3);
    }
    xc[(size_t)(4 * rq + 0) * kM + m] = make_float2(ar0, ai0);
    xc[(size_t)(4 * rq + 1) * kM + m] = make_float2(ar1, ai1);
    xc[(size_t)(4 * rq + 2) * kM + m] = make_float2(ar2, ai2);
    xc[(size_t)(4 * rq + 3) * kM + m] = make_float2(ar3, ai3);
}

// ---------------- spectral stage 2+3 fused: SHT (4-channel blocked) + channel mix ----------------
constexpr int kMT = 18;  // 90 = 5 * 18
__global__ __launch_bounds__(256) void k_sht_gmix2(const float* __restrict__ PwT,
                                                   const float2* __restrict__ xc,
                                                   const float* __restrict__ gwl,
                                                   float2* __restrict__ c2c) {
    __shared__ float2 cs[kCE][kMT];   // 6.9 KB
    int l = blockIdx.x / 5;
    int m0 = (blockIdx.x % 5) * kMT;
    int tid = threadIdx.x;

    if (tid < 12 * kMT) {
        int ig = tid / kMT, mm = tid % kMT;
        int i = ig * 4;
        int m = m0 + mm;
        float ar0 = 0, ai0 = 0, ar1 = 0, ai1 = 0, ar2 = 0, ai2 = 0, ar3 = 0, ai3 = 0;
        const float*  pw = PwT + (size_t)l * kHP * kM + m;
        const float2* x0 = xc + (size_t)(i + 0) * kHP * kM + m;
        const float2* x1 = xc + (size_t)(i + 1) * kHP * kM + m;
        const float2* x2 = xc + (size_t)(i + 2) * kHP * kM + m;
        const float2* x3 = xc + (size_t)(i + 3) * kHP * kM + m;
#pragma unroll 3
        for (int tt = 0; tt < kHP; tt++) {
            float pv = pw[tt * kM];
            float2 a = x0[tt * kM], b = x1[tt * kM], c = x2[tt * kM], d = x3[tt * kM];
            ar0 = fmaf(pv, a.x, ar0); ai0 = fmaf(pv, a.y, ai0);
            ar1 = fmaf(pv, b.x, ar1); ai1 = fmaf(pv, b.y, ai1);
            ar2 = fmaf(pv, c.x, ar2); ai2 = fmaf(pv, c.y, ai2);
            ar3 = fmaf(pv, d.x, ar3); ai3 = fmaf(pv, d.y, ai3);
        }
        cs[i + 0][mm] = make_float2(ar0, ai0);
        cs[i + 1][mm] = make_float2(ar1, ai1);
        cs[i + 2][mm] = make_float2(ar2, ai2);
        cs[i + 3][mm] = make_float2(ar3, ai3);
    }
    __syncthreads();
    for (int j = tid; j < kCE * kMT; j += 256) {
        int o = j / kMT, mm = j % kMT;
        float ar = 0.0f, ai = 0.0f;
        const float* gv = gwl + (size_t)o * kCE * kL + l;
#pragma unroll 8
        for (int i = 0; i < kCE; i++) {
            float g = gv[(size_t)i * kL];
            float2 cv = cs[i][mm];
            ar = fmaf(g, cv.x, ar);
            ai = fmaf(g, cv.y, ai);
        }
        c2c[((size_t)o * kL + l) * kM + m0 + mm] = make_float2(ar, ai);
    }
}

// ---------------- spectral stage 4+5 fused: iSHT + irfft, 4-channel blocked ----------------
constexpr int kCG = 4;
__global__ __launch_bounds__(192) void k_isht_irfft2(const float* __restrict__ PiT,
                                                     const float2* __restrict__ c2c,
                                                     const float2* __restrict__ icn,
                                                     float* __restrict__ dx) {
    __shared__ float2 xm[kCG][kM];  // 2.88 KB
    int bi = blockIdx.x;
    int t = bi % kHP;
    int c0 = (bi / kHP) * kCG;
    int tid = threadIdx.x;

    if (tid < 2 * kM) {
        int m = tid % kM;
        int cp = tid / kM;        // 0 or 1
        int ca = c0 + cp * 2;
        float ar0 = 0, ai0 = 0, ar1 = 0, ai1 = 0;
        const float*  pv  = PiT + (size_t)t * kL * kM + m;
        const float2* cva = c2c + (size_t)ca * kL * kM + m;
        const float2* cvb = cva + (size_t)kL * kM;
#pragma unroll 6
        for (int l = 0; l < kL; l++) {
            float pp = pv[(size_t)l * kM];
            float2 a = cva[(size_t)l * kM];
            float2 b = cvb[(size_t)l * kM];
            ar0 = fmaf(pp, a.x, ar0); ai0 = fmaf(pp, a.y, ai0);
            ar1 = fmaf(pp, b.x, ar1); ai1 = fmaf(pp, b.y, ai1);
        }
        xm[cp * 2 + 0][m] = make_float2(ar0, ai0);
        xm[cp * 2 + 1][m] = make_float2(ar1, ai1);
    }
    __syncthreads();
    if (tid < kWP) {
        int w = tid;
        float a0 = 0, a1 = 0, a2 = 0, a3 = 0;
#pragma unroll 6
        for (int m = 0; m < kM; m++) {
            float2 f = icn[m * kWP + w];
            float2 x0 = xm[0][m], x1 = xm[1][m], x2 = xm[2][m], x3 = xm[3][m];
            a0 = fmaf(x0.x, f.x, a0); a0 = fmaf(-x0.y, f.y, a0);
            a1 = fmaf(x1.x, f.x, a1); a1 = fmaf(-x1.y, f.y, a1);
            a2 = fmaf(x2.x, f.x, a2); a2 = fmaf(-x2.y, f.y, a2);
            a3 = fmaf(x3.x, f.x, a3); a3 = fmaf(-x3.y, f.y, a3);
        }
        dx[((size_t)(c0 + 0) * kHP + t) * kWP + w] = a0;
        dx[((size_t)(c0 + 1) * kHP + t) * kWP + w] = a1;
        dx[((size_t)(c0 + 2) * kHP + t) * kWP + w] = a2;
        dx[((size_t)(c0 + 3) * kHP + t) * kWP + w] = a3;
    }
}

// ---------------- MLP for spectral layers (in-place h update), kTP=16 ----------------
constexpr int kTP = 16;
__global__ __launch_bounds__(256) void k_mlp_f(const float* __restrict__ m1w, const float* __restrict__ m2w,
                                               const float* __restrict__ lsw, const float* __restrict__ dx,
                                               float* __restrict__ h) {
    __shared__ float xs[kCE][kTP];   // 3 KB
    __shared__ float g1[kHD][kTP];   // 6 KB
    int p0 = blockIdx.x * kTP;
    int tid = threadIdx.x;

    for (int j = tid; j < kCE * kTP; j += 256) {
        int i = j / kTP, pp = j % kTP;
        int p = p0 + pp;
        xs[i][pp] = (p < kNP) ? dx[(size_t)i * kNP + p] : 0.0f;
    }
    __syncthreads();
    for (int j = tid; j < kHD * kTP; j += 256) {
        int hh = j / kTP, pp = j % kTP;
        const float* w1 = m1w + (size_t)hh * kCE;
        float a = 0.0f;
#pragma unroll 8
        for (int i = 0; i < kCE; i++) a = fmaf(w1[i], xs[i][pp], a);
        g1[hh][pp] = gelu_tanh(a);
    }
    __syncthreads();
    for (int j = tid; j < kCE * kTP; j += 256) {
        int o = j / kTP, pp = j % kTP;
        int p = p0 + pp;
        if (p < kNP) {
            const float* w2 = m2w + (size_t)o * kHD;
            float a = 0.0f;
#pragma unroll 8
            for (int jj = 0; jj < kHD; jj++) a = fmaf(w2[jj], g1[jj][pp], a);
            size_t q = (size_t)o * kNP + p;
            h[q] = h[q] + lsw[o] * a;
        }
    }
}

// ---------------- decoder: per-point 3x3 stencil, direct from global (FINAL r8 form, unroll 2) ----------------
// Proven ~200 µs. All perturbations regressed: r9 manual pipeline (+36%), r12
// channel-split (+134%), r14 OG-split (+170%), r17 unroll-4 (+82%). The compiler's
// unroll-2 schedule is the verified local optimum.
__global__ __launch_bounds__(256) void k_dconv_d(const float* __restrict__ h,
                                                 const float* __restrict__ dvals,
                                                 const float* __restrict__ dwT,
                                                 const int* __restrict__ li0, const int* __restrict__ li1,
                                                 const float* __restrict__ lwt, const int* __restrict__ oi0,
                                                 const int* __restrict__ oi1, const float* __restrict__ owt,
                                                 float* __restrict__ out) {
    int p = blockIdx.x * 256 + threadIdx.x;
    if (p >= kNPF) return;
    int lat = p / kWF;
    int p_lon = p - lat * kWF;

    int i0r[3], i1r[3];
    float awr[3];
#pragma unroll
    for (int r = 0; r < 3; r++) {
        int Lr = lat - 1 + r;
        Lr = Lr < 0 ? 0 : (Lr > kHF - 1 ? kHF - 1 : Lr);
        i0r[r] = li0[Lr]; i1r[r] = li1[Lr]; awr[r] = lwt[Lr];
    }
    int F = min(i0r[0], min(i0r[1], i0r[2]));

    float wrow[3][3];
#pragma unroll
    for (int r = 0; r < 3; r++) {
        int r0 = i0r[r] - F, r1 = i1r[r] - F;
#pragma unroll
        for (int pr = 0; pr < 3; pr++) {
            float wv = 0.0f;
            if (pr == r0) wv += 1.0f - awr[r];
            if (pr == r1) wv += awr[r];
            wrow[r][pr] = wv;
        }
    }

    int o0d[3], o1d[3];
    float owd[3];
#pragma unroll
    for (int d = 0; d < 3; d++) {
        int lm = (p_lon + d - 1 + kWF) % kWF;
        o0d[d] = oi0[lm]; o1d[d] = oi1[lm]; owd[d] = owt[lm];
    }
    int G = o0d[0];
    float wcol[3][3];
#pragma unroll
    for (int d = 0; d < 3; d++) {
        int c0 = (o0d[d] - G + kWP) % kWP;
        int c1 = (o1d[d] - G + kWP) % kWP;
#pragma unroll
        for (int pc = 0; pc < 3; pc++) {
            float wv = 0.0f;
            if (pc == c0) wv += 1.0f - owd[d];
            if (pc == c1) wv += owd[d];
            wcol[d][pc] = wv;
        }
    }

    float vv[kK][kNB];
#pragma unroll
    for (int k = 0; k < kK; k++) {
        const float* vp = dvals + ((size_t)k * kNPF + p) * kNB;
#pragma unroll
        for (int n = 0; n < kNB; n += 2) {
            float2 v2 = *(const float2*)(vp + n);
            vv[k][n] = v2.x; vv[k][n + 1] = v2.y;
        }
    }

    const int RR[kNB] = {1, 1, 1, 2, 0, 2};
    const int CC[kNB] = {1, 2, 0, 1, 1, 2};
    float ck[kK][3][3];
#pragma unroll
    for (int k = 0; k < kK; k++)
#pragma unroll
        for (int pr = 0; pr < 3; pr++)
#pragma unroll
            for (int pc = 0; pc < 3; pc++) {
                float s = 0.0f;
#pragma unroll
                for (int n = 0; n < kNB; n++)
                    s = fmaf(vv[k][n], wrow[RR[n]][pr] * wcol[CC[n]][pc], s);
                ck[k][pr][pc] = s;
            }

    int ofs[3][3];
#pragma unroll
    for (int pr = 0; pr < 3; pr++) {
        int row = F + pr; row = row > kHP - 1 ? kHP - 1 : row;
#pragma unroll
        for (int pc = 0; pc < 3; pc++) {
            int col = (G + pc) % kWP;
            ofs[pr][pc] = row * kWP + col;
        }
    }

    float acc[kCOUT];
#pragma unroll
    for (int o = 0; o < kCOUT; o++) acc[o] = 0.0f;

    const float* wp = dwT;
    const float* hi = h;
#pragma unroll 2
    for (int i = 0; i < kCE; i++) {
        float hv[3][3];
#pragma unroll
        for (int pr = 0; pr < 3; pr++)
#pragma unroll
            for (int pc = 0; pc < 3; pc++)
                hv[pr][pc] = hi[ofs[pr][pc]];
        float z[kK];
#pragma unroll
        for (int k = 0; k < kK; k++) {
            float s = 0.0f;
#pragma unroll
            for (int pr = 0; pr < 3; pr++)
#pragma unroll
                for (int pc = 0; pc < 3; pc++)
                    s = fmaf(ck[k][pr][pc], hv[pr][pc], s);
            z[k] = s;
        }
#pragma unroll
        for (int o = 0; o < kCOUT; o++) {
            float s = acc[o];
#pragma unroll
            for (int k = 0; k < kK; k++) s = fmaf(wp[o * kK + k], z[k], s);
            acc[o] = s;
        }
        wp += kCOUT * kK;
        hi += kNP;
    }

#pragma unroll
    for (int o = 0; o < kCOUT; o++) out[(size_t)o * kNPF + p] = acc[o];
}

// ---------------- host launcher ----------------
extern "C" void kernel_launch(void* const* d_in, const int* in_sizes, int n_in,
                              void* d_out, int out_size, void* d_ws, size_t ws_size,
                              hipStream_t stream) {
    const float* x         = (const float*)d_in[0];
    const int*   enc_idx   = (const int*)d_in[1];
    const float* enc_vals  = (const float*)d_in[2];
    const float* enc_w     = (const float*)d_in[3];
    const int*   proc_idx  = (const int*)d_in[4];
    const float* proc_vals = (const float*)d_in[5];
    const float* lw        = (const float*)d_in[6];
    const float* gw        = (const float*)d_in[7];
    const float* Pw        = (const float*)d_in[8];
    const float* Pi        = (const float*)d_in[9];
    const float* m1        = (const float*)d_in[10];
    const float* m2        = (const float*)d_in[11];
    const float* ls        = (const float*)d_in[12];
    const int*   li0       = (const int*)d_in[13];
    const int*   li1       = (const int*)d_in[14];
    const float* lwt       = (const float*)d_in[15];
    const int*   oi0       = (const int*)d_in[16];
    const int*   oi1       = (const int*)d_in[17];
    const float* owt       = (const float*)d_in[18];
    const int*   dec_idx   = (const int*)d_in[19];
    const float* dec_vals  = (const float*)d_in[20];
    const float* dec_w     = (const float*)d_in[21];
    float* out = (float*)d_out;
    (void)dec_idx;

    float* ws = (float*)d_ws;
    size_t off = 0;
    auto alloc = [&](size_t n) { float* p = ws + off; off += n; return p; };
    float*  h0   = alloc((size_t)kCE * kNP);
    float*  h1   = alloc((size_t)kCE * kNP);
    float2* xc   = (float2*)alloc((size_t)2 * kCE * kHP * kM);
    float2* c2c  = (float2*)alloc((size_t)2 * kCE * kL * kM);
    float*  dx   = alloc((size_t)kCE * kNP);
    float2* fcs  = (float2*)alloc((size_t)2 * kM * kWP);
    float2* icn  = (float2*)alloc((size_t)2 * kM * kWP);
    float*  PwT  = alloc((size_t)kL * kM * kHP);
    float*  PiT  = alloc((size_t)kL * kM * kHP);
    float*  dwT  = alloc((size_t)kCOUT * kCE * kK);
    (void)ws_size; (void)in_sizes; (void)n_in; (void)out_size;

    float* hbuf[2] = {h0, h1};
    int cur = 0;

    dim3 B(256);
    auto nb = [](long long n) { return dim3((unsigned)((n + 255) / 256)); };

    k_prep<<<nb(2LL * kL * kM * kHP), B, 0, stream>>>(fcs, icn, dec_w, dwT, Pw, Pi, PwT, PiT);

    // encoder (OG=16)
    k_disco<kCIN, kCE, 16><<<nb((long long)kNP * 16), B, 0, stream>>>(
        x, kNPF, enc_idx, enc_vals, enc_w, hbuf[cur], kNP);

    int nMlpBlocks = (kNP + kTP - 1) / kTP;
    for (int i = 0; i < kNL; i++) {
        if (i % 2 == 0) {
            const float* gwl = gw + (size_t)(i / 2) * kCE * kCE * kL;
            k_rfft4<<<nb((long long)(kCE * kHP / 4) * kM), B, 0, stream>>>(hbuf[cur], fcs, xc);
            k_sht_gmix2<<<dim3(kL * 5), B, 0, stream>>>(PwT, xc, gwl, c2c);
            k_isht_irfft2<<<dim3(kHP * (kCE / kCG)), dim3(192), 0, stream>>>(PiT, c2c, icn, dx);
            k_mlp_f<<<dim3(nMlpBlocks), B, 0, stream>>>(
                m1 + (size_t)i * kHD * kCE, m2 + (size_t)i * kCE * kHD, ls + (size_t)i * kCE,
                dx, hbuf[cur]);
        } else {
            const float* lwl = lw + (size_t)(i / 2) * kCE * kCE * kK;
            k_disco_mlp<<<dim3((kNP + 15) / 16), B, 0, stream>>>(
                hbuf[cur], proc_idx, proc_vals, lwl,
                m1 + (size_t)i * kHD * kCE, m2 + (size_t)i * kCE * kHD, ls + (size_t)i * kCE,
                hbuf[1 - cur]);
            cur = 1 - cur;
        }
    }

    // decoder: r8 barrier-free direct-global stencil (final form, unroll 2)
    k_dconv_d<<<nb((long long)kNPF), B, 0, stream>>>(hbuf[cur], dec_vals, dwT,
                                                     li0, li1, lwt, oi0, oi1, owt, out);
}